// Round 1
// baseline (218.584 us; speedup 1.0000x reference)
//
#include <hip/hip_runtime.h>
#include <hip/hip_bf16.h>
#include <float.h>

#define N_NODES 100000
#define HID     512
#define NGRAPH  1024

typedef __bf16 bf16_t;
typedef bf16_t bf16x8 __attribute__((ext_vector_type(8)));
typedef float  f32x4  __attribute__((ext_vector_type(4)));

// XOR-swizzle for 128-byte LDS rows: spreads 16B slots across banks (Guideline 4).
__device__ __forceinline__ unsigned swz(unsigned byteoff) {
    return byteoff ^ (((byteoff >> 7) & 7u) << 4);
}

// ---------------- Kernel 0: W1 [K][N] f32 -> W1^T [N][K] bf16 ----------------
__global__ void __launch_bounds__(256) k_w1t(const float* __restrict__ w1,
                                             bf16_t* __restrict__ w1t) {
    int idx = blockIdx.x * 256 + threadIdx.x;   // 0 .. 262143
    int k = idx >> 9;
    int n = idx & 511;
    w1t[n * HID + k] = (bf16_t)w1[idx];
}

// ---------------- Kernel 1: fused GEMM + gelu + dot(W2) -> partial gates -----
// Block tile: 128 rows x 256 cols, BK=64. 512 threads = 8 waves (2M x 4N).
// grid.x = 1564: bidx>>1 = row-block, bidx&1 = col-half (adjacent for L2 reuse of h).
__global__ void __launch_bounds__(512) k_gemm_gate(const float* __restrict__ h,
                                                   const bf16_t* __restrict__ w1t,
                                                   const float* __restrict__ b1,
                                                   const float* __restrict__ w2,
                                                   float* __restrict__ gpart) {
    __shared__ __align__(16) bf16_t As[128 * 64];   // [row][k] 128B rows, swizzled
    __shared__ __align__(16) bf16_t Bs[256 * 64];   // [n][k]   128B rows, swizzled
    __shared__ float gp[4][128];

    const int tid  = threadIdx.x;
    const int lane = tid & 63;
    const int wv   = tid >> 6;     // 0..7
    const int wm   = wv >> 2;      // 0..1  (M half)
    const int wn   = wv & 3;       // 0..3  (N quarter)
    const int l15  = lane & 15;
    const int l4   = lane >> 4;    // 0..3

    const int bidx = blockIdx.x;
    const int brow = (bidx >> 1) * 128;
    const int bcol = (bidx & 1) * 256;

    const int sr = tid >> 3;        // 0..63
    const int sk = (tid & 7) * 8;   // element offset within K-tile

    f32x4 acc[4][4] = {};

    for (int kt = 0; kt < 8; ++kt) {
        const int k0 = kt * 64;
        // ---- stage A: h rows -> bf16, swizzled ds_write_b128 ----
        #pragma unroll
        for (int hh = 0; hh < 2; ++hh) {
            const int row  = hh * 64 + sr;
            const int grow = brow + row;
            float f[8] = {0.f, 0.f, 0.f, 0.f, 0.f, 0.f, 0.f, 0.f};
            if (grow < N_NODES) {
                const float4* p = reinterpret_cast<const float4*>(
                    h + (size_t)grow * HID + k0 + sk);
                float4 a0 = p[0], a1 = p[1];
                f[0] = a0.x; f[1] = a0.y; f[2] = a0.z; f[3] = a0.w;
                f[4] = a1.x; f[5] = a1.y; f[6] = a1.z; f[7] = a1.w;
            }
            bf16x8 v;
            #pragma unroll
            for (int j = 0; j < 8; ++j) v[j] = (bf16_t)f[j];
            *reinterpret_cast<bf16x8*>(
                reinterpret_cast<char*>(As) + swz(row * 128 + sk * 2)) = v;
        }
        // ---- stage B: W1^T rows (already bf16) ----
        #pragma unroll
        for (int q = 0; q < 4; ++q) {
            const int n = q * 64 + sr;
            bf16x8 v = *reinterpret_cast<const bf16x8*>(
                w1t + (size_t)(bcol + n) * HID + k0 + sk);
            *reinterpret_cast<bf16x8*>(
                reinterpret_cast<char*>(Bs) + swz(n * 128 + sk * 2)) = v;
        }
        __syncthreads();
        // ---- 32 MFMA per K-tile per wave ----
        #pragma unroll
        for (int ks = 0; ks < 2; ++ks) {
            bf16x8 af[4], bfr[4];
            #pragma unroll
            for (int mf = 0; mf < 4; ++mf) {
                const int row = wm * 64 + mf * 16 + l15;
                af[mf] = *reinterpret_cast<const bf16x8*>(
                    reinterpret_cast<const char*>(As) +
                    swz(row * 128 + ks * 64 + l4 * 16));
            }
            #pragma unroll
            for (int nf = 0; nf < 4; ++nf) {
                const int n = wn * 64 + nf * 16 + l15;
                bfr[nf] = *reinterpret_cast<const bf16x8*>(
                    reinterpret_cast<const char*>(Bs) +
                    swz(n * 128 + ks * 64 + l4 * 16));
            }
            #pragma unroll
            for (int mf = 0; mf < 4; ++mf)
                #pragma unroll
                for (int nf = 0; nf < 4; ++nf)
                    acc[mf][nf] = __builtin_amdgcn_mfma_f32_16x16x32_bf16(
                        af[mf], bfr[nf], acc[mf][nf], 0, 0, 0);
        }
        __syncthreads();
    }

    // ---- epilogue: gelu(acc + b1) * w2, reduce over this block's 256 cols ----
    float pr[16];
    #pragma unroll
    for (int i = 0; i < 16; ++i) pr[i] = 0.f;
    #pragma unroll
    for (int nf = 0; nf < 4; ++nf) {
        const int cg    = bcol + wn * 64 + nf * 16 + l15;
        const float b1v = b1[cg];
        const float w2v = w2[cg];
        #pragma unroll
        for (int mf = 0; mf < 4; ++mf) {
            #pragma unroll
            for (int rr = 0; rr < 4; ++rr) {
                const float x  = acc[mf][nf][rr] + b1v;
                const float ge = 0.5f * x * (1.f + erff(x * 0.70710678118654752f));
                pr[mf * 4 + rr] = fmaf(ge, w2v, pr[mf * 4 + rr]);
            }
        }
    }
    // butterfly sum over the 16-lane column group (D cols live in lane&15)
    #pragma unroll
    for (int i = 0; i < 16; ++i) {
        float v = pr[i];
        v += __shfl_xor(v, 1);
        v += __shfl_xor(v, 2);
        v += __shfl_xor(v, 4);
        v += __shfl_xor(v, 8);
        pr[i] = v;
    }
    if (l15 == 0) {
        #pragma unroll
        for (int mf = 0; mf < 4; ++mf)
            #pragma unroll
            for (int rr = 0; rr < 4; ++rr)
                gp[wn][wm * 64 + mf * 16 + l4 * 4 + rr] = pr[mf * 4 + rr];
    }
    __syncthreads();
    if (tid < 128) {
        const int grow = brow + tid;
        if (grow < N_NODES) {
            gpart[(size_t)(bidx & 1) * N_NODES + grow] =
                gp[0][tid] + gp[1][tid] + gp[2][tid] + gp[3][tid];
        }
    }
}

// ---------------- Kernel 2: combine column-half partials + b2 ----------------
__global__ void __launch_bounds__(256) k_gate_reduce(const float* __restrict__ gpart,
                                                     const float* __restrict__ b2,
                                                     float* __restrict__ gate) {
    int i = blockIdx.x * 256 + threadIdx.x;
    if (i < N_NODES) gate[i] = gpart[i] + gpart[N_NODES + i] + b2[0];
}

// ---------------- Kernel 3: segment softmax + weighted pool ------------------
// One block (256 threads) per graph. batch_vec is sorted -> binary search bounds.
__global__ void __launch_bounds__(256) k_pool(const float* __restrict__ h,
                                              const int* __restrict__ bv,
                                              const float* __restrict__ gate,
                                              float* __restrict__ out) {
    const int g   = blockIdx.x;
    const int tid = threadIdx.x;
    __shared__ int   s_bounds[2];
    __shared__ float s_red[4];
    __shared__ float s_alpha[256];

    if (tid == 0) {
        int lo = 0, hi = N_NODES;
        while (lo < hi) { int mid = (lo + hi) >> 1; if (bv[mid] < g) lo = mid + 1; else hi = mid; }
        s_bounds[0] = lo;
        int lo2 = lo, hi2 = N_NODES;
        while (lo2 < hi2) { int mid = (lo2 + hi2) >> 1; if (bv[mid] < g + 1) lo2 = mid + 1; else hi2 = mid; }
        s_bounds[1] = lo2;
    }
    __syncthreads();
    const int start = s_bounds[0], end = s_bounds[1];

    float2 acc = make_float2(0.f, 0.f);
    if (start < end) {
        const int lane = tid & 63, wv = tid >> 6;
        // pass 1: segment max
        float lm = -FLT_MAX;
        for (int i = start + tid; i < end; i += 256) lm = fmaxf(lm, gate[i]);
        #pragma unroll
        for (int o = 32; o; o >>= 1) lm = fmaxf(lm, __shfl_xor(lm, o));
        if (lane == 0) s_red[wv] = lm;
        __syncthreads();
        const float m = fmaxf(fmaxf(s_red[0], s_red[1]), fmaxf(s_red[2], s_red[3]));
        __syncthreads();
        // pass 2: denom
        float ls = 0.f;
        for (int i = start + tid; i < end; i += 256) ls += expf(gate[i] - m);
        #pragma unroll
        for (int o = 32; o; o >>= 1) ls += __shfl_xor(ls, o);
        if (lane == 0) s_red[wv] = ls;
        __syncthreads();
        const float inv = 1.f / (s_red[0] + s_red[1] + s_red[2] + s_red[3]);
        // pass 3: chunked alpha-weighted sum of h rows; 2 cols per thread
        const float* hcol = h + tid * 2;
        for (int base = start; base < end; base += 256) {
            const int j = base + tid;
            const float av = (j < end) ? expf(gate[j] - m) * inv : 0.f;
            __syncthreads();
            s_alpha[tid] = av;
            __syncthreads();
            const int cnt = min(256, end - base);
            for (int jj = 0; jj < cnt; ++jj) {
                const float a = s_alpha[jj];
                const float2 hv = *reinterpret_cast<const float2*>(
                    hcol + (size_t)(base + jj) * HID);
                acc.x = fmaf(a, hv.x, acc.x);
                acc.y = fmaf(a, hv.y, acc.y);
            }
        }
    }
    *reinterpret_cast<float2*>(out + (size_t)g * HID + tid * 2) = acc;
}

// ---------------- launcher ---------------------------------------------------
extern "C" void kernel_launch(void* const* d_in, const int* in_sizes, int n_in,
                              void* d_out, int out_size, void* d_ws, size_t ws_size,
                              hipStream_t stream) {
    const float* h  = (const float*)d_in[0];
    const int*   bv = (const int*)d_in[1];
    const float* W1 = (const float*)d_in[2];
    const float* b1 = (const float*)d_in[3];
    const float* W2 = (const float*)d_in[4];
    const float* b2 = (const float*)d_in[5];
    float* out = (float*)d_out;

    char* ws = (char*)d_ws;
    bf16_t* w1t   = (bf16_t*)ws;                           // 512*512*2 = 524288 B
    float*  gpart = (float*)(ws + 524288);                 // 2*100000*4 = 800000 B
    float*  gate  = (float*)(ws + 524288 + 800000);        // 100000*4 B

    k_w1t<<<dim3(1024), dim3(256), 0, stream>>>(W1, w1t);
    k_gemm_gate<<<dim3(1564), dim3(512), 0, stream>>>(h, w1t, b1, W2, gpart);
    k_gate_reduce<<<dim3((N_NODES + 255) / 256), dim3(256), 0, stream>>>(gpart, b2, gate);
    k_pool<<<dim3(NGRAPH), dim3(256), 0, stream>>>(h, bv, gate, out);
}